// Round 1
// baseline (58.894 us; speedup 1.0000x reference)
//
#include <hip/hip_runtime.h>
#include <math.h>

#define DD     64
#define RPB    16    // rows per block = MFMA tile M (one tile, 4 waves share it)
#define N_BF16 13    // r19: 14->13. absmax at 14 was exactly 2^-8 (bf16 ulp) =>
                     // likely quantization floor, not convergence error. Bound
                     // at 13 est <= ~1e-2 vs 2e-2 threshold.
#define N_POL  2     // split-precision polish applies
#define ZS     72    // shorts per z-image row (144 B: 16B-aligned row stride)

typedef float f4 __attribute__((ext_vector_type(4)));
typedef short s8 __attribute__((ext_vector_type(8)));   // 8 bf16 = 4 VGPRs

// r19: lambda = 2*log2(e) is PRE-SCALED into W and x, so the MFMA result is
// already the exp2 argument: tanh(a) = 1 - 2/(exp2(lam*a)+1) with lam*a coming
// straight out of the accumulator. Removes one VALU mul from every tanh's
// dependent chain. |lam*zl| <= ~40 -> exp2 in range, no clamp needed.
__device__ __forceinline__ float tanh_pre(float e_arg) {
    const float e = __builtin_amdgcn_exp2f(e_arg);
    return fmaf(-2.0f, __builtin_amdgcn_rcpf(e + 1.0f), 1.0f);
}
__device__ __forceinline__ unsigned short f2bf(float f) {
    return (unsigned short)((__float_as_uint(f) + 0x8000u) >> 16);
}
__device__ __forceinline__ float bf2f(unsigned short h) {
    return __uint_as_float(((unsigned int)h) << 16);
}

// COLUMN-SPLIT MFMA (r17 structure, HW-proven): one block = one 16-row tile,
// FOUR waves (one per SIMD) each owning 16 output columns. This split is
// deliberate: it spreads the 16 per-row tanhs across 4 SIMDs (4/wave). The
// fused-pair / single-wave alternatives were costed and LOSE: saving one
// LDS exchange (~250 cy) costs +12 serialized quarter-rate tanhs (~290 cy).
// MFMA mapping (r14 HW-verified): D = A.B + C, A = z bf16 image
// (A[m=lane&15][k=(lane>>4)*8+j]), B = W[col][k] in regs, C = x (free add);
// C/D col=lane&15, row=(lane>>4)*4+reg.
// r19 deltas: lambda pre-scale (see tanh_pre); N_BF16 13 (odd -> polish
// buffer parity flipped via sel2, see hazard note below); polish MFMAs
// regrouped 2x3 -> 3x2 dependent chains (shorter critical path).
__global__ __launch_bounds__(256)
void tanh_newton_mfma(const float* __restrict__ x,
                      const float* __restrict__ W,
                      float* __restrict__ out)
{
    __shared__ alignas(16) short zbuf[2][16 * ZS];  // bf16 hi image, dbuf
    __shared__ alignas(16) short zLo[2][16 * ZS];   // polish lo image, dbuf

    const int lane = threadIdx.x & 63;
    const int t    = threadIdx.x >> 6;    // wave id = column tile 0..3
    const int c0   = lane & 15;
    const int q    = lane >> 4;
    const int r0   = blockIdx.x * RPB;
    const int col  = 16 * t + c0;         // this lane's output column

    const float LAM = 2.885390081777927f; // 2*log2(e), folded into W and x

    // ---- W fragments for THIS wave's 16 columns, bf16 hi+lo split of LAM*W.
    s8 whi[2], wlo[2];
#pragma unroll
    for (int h = 0; h < 2; ++h) {
        const float* wp = W + col * DD + 8 * q + 32 * h;
        const float4 u = *reinterpret_cast<const float4*>(wp);
        const float4 v = *reinterpret_cast<const float4*>(wp + 4);
        const float wf[8] = {u.x, u.y, u.z, u.w, v.x, v.y, v.z, v.w};
        s8 hi8, lo8;
#pragma unroll
        for (int j = 0; j < 8; ++j) {
            const float ws = LAM * wf[j];
            const unsigned short hb = f2bf(ws);
            hi8[j] = (short)hb;
            lo8[j] = (short)f2bf(ws - bf2f(hb));
        }
        whi[h] = hi8;
        wlo[h] = lo8;
    }

    // ---- x fragment (C layout, pre-scaled) + z0 = tanh(x) = tanh_pre(LAM*x).
    f4 xf;
    float z[4];
#pragma unroll
    for (int i = 0; i < 4; ++i) {
        const float xv = LAM * x[(r0 + 4 * q + i) * DD + col];
        xf[i] = xv;
        z[i]  = tanh_pre(xv);
    }

    const f4 zero = {0.f, 0.f, 0.f, 0.f};

    // ---- phase 1: fixed-count bf16 MFMA applies, 1 barrier each.
    // Buffer-parity safety: apply it reads zbuf[it&1]; its reads complete
    // (hw waitcnt before MFMA) before it reaches apply it+1's barrier, which
    // precedes any it+2 write to the same buffer.
    for (int it = 0; it < N_BF16; ++it) {
        const int sel = it & 1;
#pragma unroll
        for (int i = 0; i < 4; ++i)
            zbuf[sel][(4 * q + i) * ZS + col] = (short)f2bf(z[i]);
        __syncthreads();
        const s8 a0 = *reinterpret_cast<const s8*>(&zbuf[sel][c0 * ZS + 8 * q]);
        const s8 a1 = *reinterpret_cast<const s8*>(&zbuf[sel][c0 * ZS + 8 * q + 32]);
        // Two independent MFMA chains (overlapped latency), then one add.
        f4 acc0 = __builtin_amdgcn_mfma_f32_16x16x32_bf16(a0, whi[0], xf,   0, 0, 0);
        f4 acc1 = __builtin_amdgcn_mfma_f32_16x16x32_bf16(a1, whi[1], zero, 0, 0, 0);
#pragma unroll
        for (int i = 0; i < 4; ++i) z[i] = tanh_pre(acc0[i] + acc1[i]);
    }

    // ---- phase 2: split-precision polish (fp32-grade, r14 HW-verified):
    // zl = Ah.Bh + Al.Bh + Ah.Bl, dropping only Al.Bl ~ 3e-8. One barrier
    // per polish. Buffer parity: N_BF16 is ODD, so polish p uses buffer
    // (N_BF16+p)&1 -- polish 0 must NOT write zbuf[0] (apply N_BF16-1's
    // reads of zbuf[0] may still be in flight in other waves); writing
    // zbuf[1] is safe since apply N_BF16-2's reads completed before apply
    // N_BF16-1's barrier. r19: the 6 MFMAs are grouped as THREE independent
    // 2-deep chains (was two 3-deep) -> shorter dependent-latency path.
    for (int p = 0; p < N_POL; ++p) {
        const int sel2 = (N_BF16 + p) & 1;
#pragma unroll
        for (int i = 0; i < 4; ++i) {
            const float zv = z[i];
            const unsigned short hb = f2bf(zv);
            zbuf[sel2][(4 * q + i) * ZS + col] = (short)hb;
            zLo[sel2][(4 * q + i) * ZS + col]  = (short)f2bf(zv - bf2f(hb));
        }
        __syncthreads();
        const s8 ah0 = *reinterpret_cast<const s8*>(&zbuf[sel2][c0 * ZS + 8 * q]);
        const s8 ah1 = *reinterpret_cast<const s8*>(&zbuf[sel2][c0 * ZS + 8 * q + 32]);
        const s8 al0 = *reinterpret_cast<const s8*>(&zLo[sel2][c0 * ZS + 8 * q]);
        const s8 al1 = *reinterpret_cast<const s8*>(&zLo[sel2][c0 * ZS + 8 * q + 32]);
        // chain A: Ah0.Bh0 + x -> + Al0.Bh0        (2 deep)
        f4 cA = __builtin_amdgcn_mfma_f32_16x16x32_bf16(ah0, whi[0], xf,   0, 0, 0);
        // chain B: Ah1.Bh1     -> + Al1.Bh1        (2 deep)
        f4 cB = __builtin_amdgcn_mfma_f32_16x16x32_bf16(ah1, whi[1], zero, 0, 0, 0);
        // chain C: Ah0.Bl0     -> + Ah1.Bl1        (2 deep)
        f4 cC = __builtin_amdgcn_mfma_f32_16x16x32_bf16(ah0, wlo[0], zero, 0, 0, 0);
        cA = __builtin_amdgcn_mfma_f32_16x16x32_bf16(al0, whi[0], cA, 0, 0, 0);
        cB = __builtin_amdgcn_mfma_f32_16x16x32_bf16(al1, whi[1], cB, 0, 0, 0);
        cC = __builtin_amdgcn_mfma_f32_16x16x32_bf16(ah1, wlo[1], cC, 0, 0, 0);
#pragma unroll
        for (int i = 0; i < 4; ++i) z[i] = tanh_pre(cA[i] + cB[i] + cC[i]);
    }

    // ---- store (C layout -> row-major)
#pragma unroll
    for (int i = 0; i < 4; ++i)
        out[(r0 + 4 * q + i) * DD + col] = z[i];
}

extern "C" void kernel_launch(void* const* d_in, const int* in_sizes, int n_in,
                              void* d_out, int out_size, void* d_ws, size_t ws_size,
                              hipStream_t stream)
{
    const float* x = (const float*)d_in[0];   // [B, 64] fp32
    const float* W = (const float*)d_in[1];   // [64, 64] fp32
    float* out     = (float*)d_out;           // [B, 64] fp32
    const int B = in_sizes[0] / DD;           // 4096
    tanh_newton_mfma<<<B / RPB, 256, 0, stream>>>(x, W, out);
}